// Round 1
// 4428.905 us; speedup vs baseline: 80.4111x; 80.4111x over previous
//
#include <hip/hip_runtime.h>

// Problem constants (fixed by setup_inputs)
#define B_    4
#define H_    32
#define W_    32
#define N_    1024      // H*W
#define CIN_  256
#define CHID_ 1024
#define C2_   512

// ---------------------------------------------------------------------------
// Tiled fp32 GEMM with a "virtual" A operand.
//   C[m][o] (+)= sum_k A_virt[m][k] * Wsl[o][k]    (+ bias when init)
// MODE 0: A_virt[m][k] = A[m*lda + k]                       (fc1 / fc2)
// MODE 1: A_virt[m][k] = A[tok(m,dyy,dxx)*lda + k] or 0     (plain conv tap)
// MODE 2: A_virt[m][k] = sum_{r<4} cw[r] * A[ci[r]*lda + k] (deform bilinear tap)
// K must be a multiple of 32; rows of A and Wsl must be 16B aligned.
// ---------------------------------------------------------------------------
#define BM 64
#define BN 64
#define BK 32

template<int MODE>
__global__ __launch_bounds__(256)
void gemm_tap(const float* __restrict__ A, int lda,
              const float* __restrict__ Wsl, int K,
              const float* __restrict__ bias,
              float* __restrict__ C, int ldo, int O,
              int init, int dyy, int dxx, int KK, int tap,
              const int4* __restrict__ cidx, const float4* __restrict__ cwt)
{
    __shared__ float As[BK][BM + 4];   // +4 pad: staging writes spread to 32 banks
    __shared__ float Ws[BK][BN + 4];

    const int tid = threadIdx.x;
    const int m0 = blockIdx.y * BM;
    const int o0 = blockIdx.x * BN;

    // staging assignment: lm = row (0..63), kc = k offset {0,4,8,12} (+16 second half)
    const int lm = tid >> 2;
    const int kc = (tid & 3) << 2;

    // hoist per-row A-source descriptor
    const int m = m0 + lm;
    const float* arow0 = nullptr;
    int4 ci = {0, 0, 0, 0};
    float4 cw = {0.f, 0.f, 0.f, 0.f};
    if constexpr (MODE == 0) {
        arow0 = A + (size_t)m * lda;
    } else if constexpr (MODE == 1) {
        const int b = m >> 10, n = m & (N_ - 1);
        const int y = (n >> 5) + dyy, x = (n & 31) + dxx;
        const bool v = (y >= 0 && y < H_ && x >= 0 && x < W_);
        arow0 = v ? (A + (size_t)((b << 10) | (y << 5) | x) * lda) : nullptr;
    } else {
        ci = cidx[(size_t)m * KK + tap];
        cw = cwt[(size_t)m * KK + tap];
    }
    const float* wrow = (o0 + lm < O) ? (Wsl + (size_t)(o0 + lm) * K) : nullptr;

    // compute assignment: thread (ty,tx) owns rows ty*4..+3, cols tx*4..+3
    const int ty = tid >> 4;
    const int tx = tid & 15;

    float acc[4][4] = {};

    for (int k0 = 0; k0 < K; k0 += BK) {
        float4 av[2], wv[2];
#pragma unroll
        for (int h2 = 0; h2 < 2; ++h2) {
            const int kk = k0 + kc + h2 * 16;
            if constexpr (MODE == 2) {
                const float4 v0 = *(const float4*)(A + (size_t)ci.x * lda + kk);
                const float4 v1 = *(const float4*)(A + (size_t)ci.y * lda + kk);
                const float4 v2 = *(const float4*)(A + (size_t)ci.z * lda + kk);
                const float4 v3 = *(const float4*)(A + (size_t)ci.w * lda + kk);
                float4 s;
                s.x = cw.x * v0.x + cw.y * v1.x + cw.z * v2.x + cw.w * v3.x;
                s.y = cw.x * v0.y + cw.y * v1.y + cw.z * v2.y + cw.w * v3.y;
                s.z = cw.x * v0.z + cw.y * v1.z + cw.z * v2.z + cw.w * v3.z;
                s.w = cw.x * v0.w + cw.y * v1.w + cw.z * v2.w + cw.w * v3.w;
                av[h2] = s;
            } else {
                av[h2] = arow0 ? *(const float4*)(arow0 + kk)
                               : make_float4(0.f, 0.f, 0.f, 0.f);
            }
            wv[h2] = wrow ? *(const float4*)(wrow + kk)
                          : make_float4(0.f, 0.f, 0.f, 0.f);
        }
        __syncthreads();   // previous chunk's LDS reads complete
#pragma unroll
        for (int h2 = 0; h2 < 2; ++h2) {
            const int kb = kc + h2 * 16;
            As[kb + 0][lm] = av[h2].x; As[kb + 1][lm] = av[h2].y;
            As[kb + 2][lm] = av[h2].z; As[kb + 3][lm] = av[h2].w;
            Ws[kb + 0][lm] = wv[h2].x; Ws[kb + 1][lm] = wv[h2].y;
            Ws[kb + 2][lm] = wv[h2].z; Ws[kb + 3][lm] = wv[h2].w;
        }
        __syncthreads();   // tiles visible
#pragma unroll
        for (int k = 0; k < BK; ++k) {
            const float4 a4 = *(const float4*)&As[k][ty << 2];
            const float4 b4 = *(const float4*)&Ws[k][tx << 2];
            const float a[4] = {a4.x, a4.y, a4.z, a4.w};
            const float b[4] = {b4.x, b4.y, b4.z, b4.w};
#pragma unroll
            for (int i = 0; i < 4; ++i)
#pragma unroll
                for (int j = 0; j < 4; ++j)
                    acc[i][j] += a[i] * b[j];
        }
        __syncthreads();   // done reading before next overwrite
    }

#pragma unroll
    for (int i = 0; i < 4; ++i) {
        const int mm = m0 + (ty << 2) + i;
        float* crow = C + (size_t)mm * ldo;
#pragma unroll
        for (int j = 0; j < 4; ++j) {
            const int oo = o0 + (tx << 2) + j;
            if (oo < O)
                crow[oo] = acc[i][j] + (init ? bias[oo] : crow[oo]);
        }
    }
}

// ---------------------------------------------------------------------------
// Repack one tap slice: out[o*C + c] = w[(o*C + c)*KK + t]   (w is [O][C][KK])
// ---------------------------------------------------------------------------
__global__ void repack_slice(const float* __restrict__ w, float* __restrict__ out,
                             int total, int KK, int t)
{
    const int gid = blockIdx.x * blockDim.x + threadIdx.x;
    if (gid < total) out[gid] = w[(size_t)gid * KK + t];
}

// ---------------------------------------------------------------------------
// Bilinear coefficients per (token m, tap t): 4 clamped gather tokens + 4
// weights (validity folded in). Matches the reference corner() semantics.
// ---------------------------------------------------------------------------
template<int KS>
__global__ void coeff_kernel(const float* __restrict__ offb, int KK2,
                             int4* __restrict__ cidx, float4* __restrict__ cwt)
{
    const int KK = KS * KS, PAD = KS / 2;
    const int gid = blockIdx.x * blockDim.x + threadIdx.x;
    if (gid >= B_ * N_ * KK) return;
    const int t = gid % KK;
    const int n = (gid / KK) & (N_ - 1);
    const int b = gid / (KK * N_);
    const int mtok = b * N_ + n;

    const float dy = offb[(size_t)mtok * KK2 + 2 * t];
    const float dx = offb[(size_t)mtok * KK2 + 2 * t + 1];
    const int y = n >> 5, x = n & 31;
    const float py = (float)(y - PAD + t / KS) + dy;
    const float px = (float)(x - PAD + t % KS) + dx;
    const float y0f = floorf(py), x0f = floorf(px);
    const float fy = py - y0f, fx = px - x0f;
    const int y0 = (int)y0f, x0 = (int)x0f;

    int idx[4]; float wt[4];
    const int   yy[4] = {y0, y0, y0 + 1, y0 + 1};
    const int   xx[4] = {x0, x0 + 1, x0, x0 + 1};
    const float ww[4] = {(1.f - fy) * (1.f - fx), (1.f - fy) * fx,
                         fy * (1.f - fx),         fy * fx};
#pragma unroll
    for (int r = 0; r < 4; ++r) {
        const bool v = (yy[r] >= 0 && yy[r] < H_ && xx[r] >= 0 && xx[r] < W_);
        const int yc = min(max(yy[r], 0), H_ - 1);
        const int xc = min(max(xx[r], 0), W_ - 1);
        idx[r] = b * N_ + yc * W_ + xc;
        wt[r] = v ? ww[r] : 0.f;
    }
    cidx[(size_t)mtok * KK + t] = make_int4(idx[0], idx[1], idx[2], idx[3]);
    cwt[(size_t)mtok * KK + t] = make_float4(wt[0], wt[1], wt[2], wt[3]);
}

// ---------------------------------------------------------------------------
// LayerNorm + exact GELU: one block (256 thr) per token, 4 channels/thread.
// ---------------------------------------------------------------------------
__global__ __launch_bounds__(256)
void ln_gelu(float* __restrict__ ytok, const float* __restrict__ g,
             const float* __restrict__ bt)
{
    const int t = blockIdx.x;
    const int tid = threadIdx.x;
    float* row = ytok + (size_t)t * CHID_;

    float4 v = *(const float4*)&row[tid << 2];
    __shared__ float red[4];

    float s = v.x + v.y + v.z + v.w;
#pragma unroll
    for (int o = 32; o > 0; o >>= 1) s += __shfl_down(s, o, 64);
    if ((tid & 63) == 0) red[tid >> 6] = s;
    __syncthreads();
    const float mean = (red[0] + red[1] + red[2] + red[3]) * (1.f / CHID_);

    const float d0 = v.x - mean, d1 = v.y - mean, d2 = v.z - mean, d3 = v.w - mean;
    float q = d0 * d0 + d1 * d1 + d2 * d2 + d3 * d3;
#pragma unroll
    for (int o = 32; o > 0; o >>= 1) q += __shfl_down(q, o, 64);
    __syncthreads();
    if ((tid & 63) == 0) red[tid >> 6] = q;
    __syncthreads();
    const float var = (red[0] + red[1] + red[2] + red[3]) * (1.f / CHID_);
    const float rstd = rsqrtf(var + 1e-5f);

    const float4 gv = *(const float4*)&g[tid << 2];
    const float4 bv = *(const float4*)&bt[tid << 2];
    float o0 = d0 * rstd * gv.x + bv.x;
    float o1 = d1 * rstd * gv.y + bv.y;
    float o2 = d2 * rstd * gv.z + bv.z;
    float o3 = d3 * rstd * gv.w + bv.w;
    o0 = 0.5f * o0 * (1.f + erff(o0 * 0.70710678118654752f));
    o1 = 0.5f * o1 * (1.f + erff(o1 * 0.70710678118654752f));
    o2 = 0.5f * o2 * (1.f + erff(o2 * 0.70710678118654752f));
    o3 = 0.5f * o3 * (1.f + erff(o3 * 0.70710678118654752f));
    *(float4*)&row[tid << 2] = make_float4(o0, o1, o2, o3);
}

// ---------------------------------------------------------------------------
extern "C" void kernel_launch(void* const* d_in, const int* in_sizes, int n_in,
                              void* d_out, int out_size, void* d_ws, size_t ws_size,
                              hipStream_t stream) {
    const float* x       = (const float*)d_in[0];
    const float* fc1_w   = (const float*)d_in[3];
    const float* fc1_b   = (const float*)d_in[4];
    const float* off3_w  = (const float*)d_in[5];
    const float* off3_b  = (const float*)d_in[6];
    const float* conv3_w = (const float*)d_in[7];
    const float* conv3_b = (const float*)d_in[8];
    const float* off5_w  = (const float*)d_in[9];
    const float* off5_b  = (const float*)d_in[10];
    const float* conv5_w = (const float*)d_in[11];
    const float* conv5_b = (const float*)d_in[12];
    const float* ln_g    = (const float*)d_in[13];
    const float* ln_b    = (const float*)d_in[14];
    const float* fc2_w   = (const float*)d_in[15];
    const float* fc2_b   = (const float*)d_in[16];
    float* out = (float*)d_out;   // fp32 output (R14 probe: bf16 ruled out)

    // Workspace layout (~29 MB total, well inside the 51.2 MB verified floor).
    // h doubles as ytok: branch-k output overwrites the h half that branch
    // has already fully consumed (stream-ordered, column-disjoint halves).
    char* ws = (char*)d_ws;
    float*  h    = (float*)(ws);                  // 16,777,216  [4096][1024]
    float*  dacc = (float*)(ws + 16777216);       //  8,388,608  [4096][512]
    float*  offb = (float*)(ws + 25165824);       //    819,200  [4096][<=50]
    int4*   cidx = (int4*)(ws + 25985024);        //  1,638,400  [4096][<=25]
    float4* cwt  = (float4*)(ws + 27623424);      //  1,638,400  [4096][<=25]
    float*  wsl  = (float*)(ws + 29261824);       //  1,048,576  [512][512] slice

    const dim3 TB(256);
    const int MT = (B_ * N_) / BM;   // 64 m-tiles

    // fc1: h = x @ fc1_w^T + b   (weights already [O][K] contiguous)
    gemm_tap<0><<<dim3(CHID_ / BN, MT), TB, 0, stream>>>(
        x, CIN_, fc1_w, CIN_, fc1_b, h, CHID_, CHID_, 1, 0, 0, 0, 0, nullptr, nullptr);

    // ---- branch 1 (k=3, pad=1), channels [0:512) of h ----
    for (int j = 0; j < 9; ++j) {
        repack_slice<<<(18 * C2_ + 255) / 256, TB, 0, stream>>>(off3_w, wsl, 18 * C2_, 9, j);
        gemm_tap<1><<<dim3(1, MT), TB, 0, stream>>>(
            h, CHID_, wsl, C2_, off3_b, offb, 18, 18, j == 0,
            j / 3 - 1, j % 3 - 1, 0, 0, nullptr, nullptr);
    }
    coeff_kernel<3><<<(B_ * N_ * 9 + 255) / 256, TB, 0, stream>>>(offb, 18, cidx, cwt);
    for (int j = 0; j < 9; ++j) {
        repack_slice<<<(C2_ * C2_ + 255) / 256, TB, 0, stream>>>(conv3_w, wsl, C2_ * C2_, 9, j);
        gemm_tap<2><<<dim3(C2_ / BN, MT), TB, 0, stream>>>(
            h, CHID_, wsl, C2_, conv3_b, dacc, C2_, C2_, j == 0,
            0, 0, 9, j, cidx, cwt);
    }
    for (int j = 0; j < 9; ++j) {
        repack_slice<<<(C2_ * C2_ + 255) / 256, TB, 0, stream>>>(conv3_w, wsl, C2_ * C2_, 9, j);
        gemm_tap<1><<<dim3(C2_ / BN, MT), TB, 0, stream>>>(
            dacc, C2_, wsl, C2_, conv3_b, h /*ytok[:, :512]*/, CHID_, C2_, j == 0,
            j / 3 - 1, j % 3 - 1, 0, 0, nullptr, nullptr);
    }

    // ---- branch 2 (k=5, pad=2), channels [512:1024) of h ----
    for (int j = 0; j < 25; ++j) {
        repack_slice<<<(50 * C2_ + 255) / 256, TB, 0, stream>>>(off5_w, wsl, 50 * C2_, 25, j);
        gemm_tap<1><<<dim3(1, MT), TB, 0, stream>>>(
            h + C2_, CHID_, wsl, C2_, off5_b, offb, 50, 50, j == 0,
            j / 5 - 2, j % 5 - 2, 0, 0, nullptr, nullptr);
    }
    coeff_kernel<5><<<(B_ * N_ * 25 + 255) / 256, TB, 0, stream>>>(offb, 50, cidx, cwt);
    for (int j = 0; j < 25; ++j) {
        repack_slice<<<(C2_ * C2_ + 255) / 256, TB, 0, stream>>>(conv5_w, wsl, C2_ * C2_, 25, j);
        gemm_tap<2><<<dim3(C2_ / BN, MT), TB, 0, stream>>>(
            h + C2_, CHID_, wsl, C2_, conv5_b, dacc, C2_, C2_, j == 0,
            0, 0, 25, j, cidx, cwt);
    }
    for (int j = 0; j < 25; ++j) {
        repack_slice<<<(C2_ * C2_ + 255) / 256, TB, 0, stream>>>(conv5_w, wsl, C2_ * C2_, 25, j);
        gemm_tap<1><<<dim3(C2_ / BN, MT), TB, 0, stream>>>(
            dacc, C2_, wsl, C2_, conv5_b, h + C2_ /*ytok[:, 512:]*/, CHID_, C2_, j == 0,
            j / 5 - 2, j % 5 - 2, 0, 0, nullptr, nullptr);
    }

    // LN + GELU over h (== ytok), then fc2 -> fp32 out
    ln_gelu<<<B_ * N_, TB, 0, stream>>>(h, ln_g, ln_b);
    gemm_tap<0><<<dim3(CIN_ / BN, MT), TB, 0, stream>>>(
        h, CHID_, fc2_w, CHID_, fc2_b, out, CIN_, CIN_, 1, 0, 0, 0, 0, nullptr, nullptr);
}

// Round 2
// 1424.573 us; speedup vs baseline: 249.9930x; 3.1089x over previous
//
#include <hip/hip_runtime.h>

// Problem constants (fixed by setup_inputs)
#define B_    4
#define H_    32
#define W_    32
#define N_    1024      // H*W
#define CIN_  256
#define CHID_ 1024
#define C2_   512

typedef __attribute__((ext_vector_type(8))) short short8b;   // 8 bf16 (4 VGPR)
typedef __attribute__((ext_vector_type(4))) float f32x4;     // MFMA acc

// fp32 -> bf16 (RNE), two at a time packed into a uint
__device__ __forceinline__ unsigned int f2bf2(float lo, float hi) {
    unsigned int ul = __float_as_uint(lo);
    unsigned int uh = __float_as_uint(hi);
    ul += 0x7fffu + ((ul >> 16) & 1u);
    uh += 0x7fffu + ((uh >> 16) & 1u);
    return (ul >> 16) | (uh & 0xffff0000u);
}
__device__ __forceinline__ unsigned short f2bf(float f) {
    unsigned int u = __float_as_uint(f);
    u += 0x7fffu + ((u >> 16) & 1u);
    return (unsigned short)(u >> 16);
}

// LDS tile geometry: 2 K32-subtiles; rows padded to 40 ushorts (80 B stride)
// 80 B stride => consecutive rows land 20 banks apart => fragment reads are
// 2-way bank-aliased (free, m136). Tile = 64 rows x 32 k bf16 per subtile.
#define ROWP 40
#define SUBT (64 * ROWP)

// ---------------------------------------------------------------------------
// bf16-MFMA GEMM with virtual A operand and taps folded into K.
//   C[m][o] = bias[o] + sum_{k<Ktot} A_virt[m][k] * Wb[o][k]
// k = t*512 + c for conv modes (tap t, channel c). Kc fixed at 512.
// MODE 0: A_virt[m][k] = A[m*lda + k]                     (fc1 / fc2)
// MODE 1: A_virt[m][t*512+c] = A[shift(m,t)*lda + c] or 0 (plain conv)
// MODE 2: A_virt[m][t*512+c] = sum_r cw[r] * A[ci[r]*lda + c]  (deform)
// Block: 256 thr = 4 waves (2x2), tile 64x64, wave subtile 32x32.
// Ktot must be a multiple of 64; M multiple of 64. O <= gridDim.x*64.
// ---------------------------------------------------------------------------
template<int MODE, int KS>
__global__ __launch_bounds__(256)
void gemm_mfma(const float* __restrict__ A, int lda,
               const unsigned short* __restrict__ Wb, int Ktot,
               const float* __restrict__ bias,
               float* __restrict__ C, int ldo, int O,
               const int4* __restrict__ cidx, const float4* __restrict__ cwt)
{
    __shared__ unsigned short As[2 * SUBT];
    __shared__ unsigned short Bs[2 * SUBT];

    const int tid = threadIdx.x;
    const int m0  = blockIdx.y * 64;
    const int o0  = blockIdx.x * 64;

    // ---- staging role: row = tid>>2, 16-k chunk = tid&3 ----
    const int srow = tid >> 2;
    const int skc  = tid & 3;
    const int PAD  = KS / 2;
    const int KK   = KS * KS;

    const int am = m0 + srow;            // token row for A staging
    const int an = am & (N_ - 1);
    const int ab = am >> 10;
    const int ay = an >> 5, ax = an & 31;

    const int wo = o0 + srow;            // weight row for B staging
    const unsigned short* wrow = (wo < O) ? (Wb + (size_t)wo * Ktot) : nullptr;

    // ---- compute role ----
    const int lane = tid & 63;
    const int wid  = tid >> 6;
    const int wr   = (wid >> 1) * 32;    // wave's row offset in 64x64 tile
    const int wc   = (wid & 1) * 32;
    const int l15  = lane & 15;
    const int lk   = (lane >> 4) * 8;    // lane's k-offset inside fragment

    f32x4 acc[2][2];
#pragma unroll
    for (int i = 0; i < 2; ++i)
#pragma unroll
        for (int j = 0; j < 2; ++j)
            acc[i][j] = (f32x4){0.f, 0.f, 0.f, 0.f};

    const int abase = (skc >> 1) * SUBT + srow * ROWP + (skc & 1) * 16;

    for (int k0 = 0; k0 < Ktot; k0 += 64) {
        const int kb = k0 + skc * 16;    // this thread's 16-k start
        float a[16];

        // ---------- global -> regs (A) ----------
        if constexpr (MODE == 0) {
            const float4* p = (const float4*)(A + (size_t)am * lda + kb);
#pragma unroll
            for (int q = 0; q < 4; ++q) {
                float4 v = p[q];
                a[4*q+0] = v.x; a[4*q+1] = v.y; a[4*q+2] = v.z; a[4*q+3] = v.w;
            }
        } else if constexpr (MODE == 1) {
            const int t  = kb >> 9;          // tap (Kc = 512)
            const int c0 = kb & 511;
            const int yy = ay + t / KS - PAD;
            const int xx = ax + t % KS - PAD;
            if (yy >= 0 && yy < H_ && xx >= 0 && xx < W_) {
                const float4* p = (const float4*)
                    (A + (size_t)((ab << 10) | (yy << 5) | xx) * lda + c0);
#pragma unroll
                for (int q = 0; q < 4; ++q) {
                    float4 v = p[q];
                    a[4*q+0] = v.x; a[4*q+1] = v.y; a[4*q+2] = v.z; a[4*q+3] = v.w;
                }
            } else {
#pragma unroll
                for (int q = 0; q < 16; ++q) a[q] = 0.f;
            }
        } else {
            const int t  = kb >> 9;
            const int c0 = kb & 511;
            const int4   ci = cidx[(size_t)am * KK + t];
            const float4 cw = cwt [(size_t)am * KK + t];
            const float4* p0 = (const float4*)(A + (size_t)ci.x * lda + c0);
            const float4* p1 = (const float4*)(A + (size_t)ci.y * lda + c0);
            const float4* p2 = (const float4*)(A + (size_t)ci.z * lda + c0);
            const float4* p3 = (const float4*)(A + (size_t)ci.w * lda + c0);
#pragma unroll
            for (int q = 0; q < 4; ++q) {
                float4 v0 = p0[q], v1 = p1[q], v2 = p2[q], v3 = p3[q];
                a[4*q+0] = cw.x*v0.x + cw.y*v1.x + cw.z*v2.x + cw.w*v3.x;
                a[4*q+1] = cw.x*v0.y + cw.y*v1.y + cw.z*v2.y + cw.w*v3.y;
                a[4*q+2] = cw.x*v0.z + cw.y*v1.z + cw.z*v2.z + cw.w*v3.z;
                a[4*q+3] = cw.x*v0.w + cw.y*v1.w + cw.z*v2.w + cw.w*v3.w;
            }
        }

        // pack A to bf16
        unsigned int ap[8];
#pragma unroll
        for (int q = 0; q < 8; ++q) ap[q] = f2bf2(a[2*q], a[2*q+1]);

        // ---------- global -> regs (B, already bf16) ----------
        uint4 w0, w1;
        if (wrow) {
            const uint4* p = (const uint4*)(wrow + kb);
            w0 = p[0]; w1 = p[1];
        } else {
            w0 = make_uint4(0u, 0u, 0u, 0u);
            w1 = make_uint4(0u, 0u, 0u, 0u);
        }

        __syncthreads();   // all waves done reading previous tile
        *(uint4*)&As[abase]     = make_uint4(ap[0], ap[1], ap[2], ap[3]);
        *(uint4*)&As[abase + 8] = make_uint4(ap[4], ap[5], ap[6], ap[7]);
        *(uint4*)&Bs[abase]     = w0;
        *(uint4*)&Bs[abase + 8] = w1;
        __syncthreads();   // tile visible

        // ---------- MFMA over the two K32 subtiles ----------
#pragma unroll
        for (int s = 0; s < 2; ++s) {
            const unsigned short* as = As + s * SUBT;
            const unsigned short* bs = Bs + s * SUBT;
            short8b af[2], bf[2];
#pragma unroll
            for (int i = 0; i < 2; ++i) {
                af[i] = *(const short8b*)(as + (wr + i*16 + l15) * ROWP + lk);
                bf[i] = *(const short8b*)(bs + (wc + i*16 + l15) * ROWP + lk);
            }
#pragma unroll
            for (int i = 0; i < 2; ++i)
#pragma unroll
                for (int j = 0; j < 2; ++j)
                    acc[i][j] = __builtin_amdgcn_mfma_f32_16x16x32_bf16(
                        af[i], bf[j], acc[i][j], 0, 0, 0);
        }
    }

    // ---------- epilogue: C/D layout col=lane&15, row=(lane>>4)*4+r ----------
    const int row0 = m0 + wr + (lane >> 4) * 4;
    const int col0 = o0 + wc + l15;
#pragma unroll
    for (int j = 0; j < 2; ++j) {
        const int cc = col0 + j * 16;
        if (cc < O) {
            const float bv = bias[cc];
#pragma unroll
            for (int i = 0; i < 2; ++i) {
#pragma unroll
                for (int r = 0; r < 4; ++r)
                    C[(size_t)(row0 + i*16 + r) * ldo + cc] = acc[i][j][r] + bv;
            }
        }
    }
}

// ---------------------------------------------------------------------------
// Weight repacks (once per call; weights are L3-resident, cheap)
// ---------------------------------------------------------------------------
__global__ void cast_bf(const float* __restrict__ w, unsigned short* __restrict__ o, int n)
{
    int g = blockIdx.x * blockDim.x + threadIdx.x;
    if (g < n) o[g] = f2bf(w[g]);
}

// wb[o][t*Kc + c] = (bf16) w[(o*Kc + c)*KK + t]   — coalesced reads
__global__ void fold_bf(const float* __restrict__ w, unsigned short* __restrict__ ob,
                        int O, int Kc, int KK)
{
    int g = blockIdx.x * blockDim.x + threadIdx.x;
    if (g >= O * Kc * KK) return;
    int t = g % KK;
    int c = (g / KK) % Kc;
    int o = g / (KK * Kc);
    ob[(size_t)o * (Kc * KK) + t * Kc + c] = f2bf(w[g]);
}

// ---------------------------------------------------------------------------
// Bilinear coefficients per (token m, tap t)  [unchanged, verified]
// ---------------------------------------------------------------------------
template<int KS>
__global__ void coeff_kernel(const float* __restrict__ offb, int KK2,
                             int4* __restrict__ cidx, float4* __restrict__ cwt)
{
    const int KK = KS * KS, PAD = KS / 2;
    const int gid = blockIdx.x * blockDim.x + threadIdx.x;
    if (gid >= B_ * N_ * KK) return;
    const int t = gid % KK;
    const int n = (gid / KK) & (N_ - 1);
    const int b = gid / (KK * N_);
    const int mtok = b * N_ + n;

    const float dy = offb[(size_t)mtok * KK2 + 2 * t];
    const float dx = offb[(size_t)mtok * KK2 + 2 * t + 1];
    const int y = n >> 5, x = n & 31;
    const float py = (float)(y - PAD + t / KS) + dy;
    const float px = (float)(x - PAD + t % KS) + dx;
    const float y0f = floorf(py), x0f = floorf(px);
    const float fy = py - y0f, fx = px - x0f;
    const int y0 = (int)y0f, x0 = (int)x0f;

    int idx[4]; float wt[4];
    const int   yy[4] = {y0, y0, y0 + 1, y0 + 1};
    const int   xx[4] = {x0, x0 + 1, x0, x0 + 1};
    const float ww[4] = {(1.f - fy) * (1.f - fx), (1.f - fy) * fx,
                         fy * (1.f - fx),         fy * fx};
#pragma unroll
    for (int r = 0; r < 4; ++r) {
        const bool v = (yy[r] >= 0 && yy[r] < H_ && xx[r] >= 0 && xx[r] < W_);
        const int yc = min(max(yy[r], 0), H_ - 1);
        const int xc = min(max(xx[r], 0), W_ - 1);
        idx[r] = b * N_ + yc * W_ + xc;
        wt[r] = v ? ww[r] : 0.f;
    }
    cidx[(size_t)mtok * KK + t] = make_int4(idx[0], idx[1], idx[2], idx[3]);
    cwt[(size_t)mtok * KK + t] = make_float4(wt[0], wt[1], wt[2], wt[3]);
}

// ---------------------------------------------------------------------------
// LayerNorm + exact GELU  [unchanged, verified]
// ---------------------------------------------------------------------------
__global__ __launch_bounds__(256)
void ln_gelu(float* __restrict__ ytok, const float* __restrict__ g,
             const float* __restrict__ bt)
{
    const int t = blockIdx.x;
    const int tid = threadIdx.x;
    float* row = ytok + (size_t)t * CHID_;

    float4 v = *(const float4*)&row[tid << 2];
    __shared__ float red[4];

    float s = v.x + v.y + v.z + v.w;
#pragma unroll
    for (int o = 32; o > 0; o >>= 1) s += __shfl_down(s, o, 64);
    if ((tid & 63) == 0) red[tid >> 6] = s;
    __syncthreads();
    const float mean = (red[0] + red[1] + red[2] + red[3]) * (1.f / CHID_);

    const float d0 = v.x - mean, d1 = v.y - mean, d2 = v.z - mean, d3 = v.w - mean;
    float q = d0 * d0 + d1 * d1 + d2 * d2 + d3 * d3;
#pragma unroll
    for (int o = 32; o > 0; o >>= 1) q += __shfl_down(q, o, 64);
    __syncthreads();
    if ((tid & 63) == 0) red[tid >> 6] = q;
    __syncthreads();
    const float var = (red[0] + red[1] + red[2] + red[3]) * (1.f / CHID_);
    const float rstd = rsqrtf(var + 1e-5f);

    const float4 gv = *(const float4*)&g[tid << 2];
    const float4 bv = *(const float4*)&bt[tid << 2];
    float o0 = d0 * rstd * gv.x + bv.x;
    float o1 = d1 * rstd * gv.y + bv.y;
    float o2 = d2 * rstd * gv.z + bv.z;
    float o3 = d3 * rstd * gv.w + bv.w;
    o0 = 0.5f * o0 * (1.f + erff(o0 * 0.70710678118654752f));
    o1 = 0.5f * o1 * (1.f + erff(o1 * 0.70710678118654752f));
    o2 = 0.5f * o2 * (1.f + erff(o2 * 0.70710678118654752f));
    o3 = 0.5f * o3 * (1.f + erff(o3 * 0.70710678118654752f));
    *(float4*)&row[tid << 2] = make_float4(o0, o1, o2, o3);
}

// ---------------------------------------------------------------------------
extern "C" void kernel_launch(void* const* d_in, const int* in_sizes, int n_in,
                              void* d_out, int out_size, void* d_ws, size_t ws_size,
                              hipStream_t stream) {
    const float* x       = (const float*)d_in[0];
    const float* fc1_w   = (const float*)d_in[3];
    const float* fc1_b   = (const float*)d_in[4];
    const float* off3_w  = (const float*)d_in[5];
    const float* off3_b  = (const float*)d_in[6];
    const float* conv3_w = (const float*)d_in[7];
    const float* conv3_b = (const float*)d_in[8];
    const float* off5_w  = (const float*)d_in[9];
    const float* off5_b  = (const float*)d_in[10];
    const float* conv5_w = (const float*)d_in[11];
    const float* conv5_b = (const float*)d_in[12];
    const float* ln_g    = (const float*)d_in[13];
    const float* ln_b    = (const float*)d_in[14];
    const float* fc2_w   = (const float*)d_in[15];
    const float* fc2_b   = (const float*)d_in[16];
    float* out = (float*)d_out;   // fp32 output

    // Workspace layout (49.6 MB < 51.2 MB verified floor).
    // All activations stay fp32; weights are repacked to bf16 once per call.
    char* ws = (char*)d_ws;
    float*          h    = (float*)(ws);                      // [4096][1024] fp32
    float*          dacc = (float*)(ws + 16777216);           // [4096][512]  fp32
    float*          offb = (float*)(ws + 25165824);           // [4096][<=50] fp32
    int4*           cidx = (int4*) (ws + 25985024);           // [4096][<=25]
    float4*         cwt  = (float4*)(ws + 27623424);          // [4096][<=25]
    unsigned short* fc1wb   = (unsigned short*)(ws + 29261824); // [1024][256]
    unsigned short* fc2wb   = (unsigned short*)(ws + 29786112); // [256][1024]
    unsigned short* off3wb  = (unsigned short*)(ws + 30310400); // [18][4608]
    unsigned short* off5wb  = (unsigned short*)(ws + 30476288); // [50][12800]
    unsigned short* conv3wb = (unsigned short*)(ws + 31756288); // [512][4608]
    unsigned short* conv5wb = (unsigned short*)(ws + 36474880); // [512][12800]

    const dim3 TB(256);
    const int MT = (B_ * N_) / 64;   // 64 m-tiles

    // ---- weight repacks (independent of activations) ----
    cast_bf<<<(CHID_*CIN_ + 255)/256, TB, 0, stream>>>(fc1_w, fc1wb, CHID_*CIN_);
    cast_bf<<<(CIN_*CHID_ + 255)/256, TB, 0, stream>>>(fc2_w, fc2wb, CIN_*CHID_);
    fold_bf<<<(18*C2_*9   + 255)/256, TB, 0, stream>>>(off3_w,  off3wb,  18,  C2_, 9);
    fold_bf<<<(50*C2_*25  + 255)/256, TB, 0, stream>>>(off5_w,  off5wb,  50,  C2_, 25);
    fold_bf<<<(C2_*C2_*9  + 255)/256, TB, 0, stream>>>(conv3_w, conv3wb, C2_, C2_, 9);
    fold_bf<<<(C2_*C2_*25 + 255)/256, TB, 0, stream>>>(conv5_w, conv5wb, C2_, C2_, 25);

    // ---- fc1: h = x @ fc1_w^T + b ----
    gemm_mfma<0,1><<<dim3(CHID_/64, MT), TB, 0, stream>>>(
        x, CIN_, fc1wb, CIN_, fc1_b, h, CHID_, CHID_, nullptr, nullptr);

    // ---- branch 1 (k=3): offsets -> coeffs -> deform conv -> plain conv ----
    gemm_mfma<1,3><<<dim3(1, MT), TB, 0, stream>>>(
        h, CHID_, off3wb, 9*C2_, off3_b, offb, 18, 18, nullptr, nullptr);
    coeff_kernel<3><<<(B_*N_*9 + 255)/256, TB, 0, stream>>>(offb, 18, cidx, cwt);
    gemm_mfma<2,3><<<dim3(C2_/64, MT), TB, 0, stream>>>(
        h, CHID_, conv3wb, 9*C2_, conv3_b, dacc, C2_, C2_, cidx, cwt);
    gemm_mfma<1,3><<<dim3(C2_/64, MT), TB, 0, stream>>>(
        dacc, C2_, conv3wb, 9*C2_, conv3_b, h /*ytok[:, :512]*/, CHID_, C2_,
        nullptr, nullptr);

    // ---- branch 2 (k=5) ----
    gemm_mfma<1,5><<<dim3(1, MT), TB, 0, stream>>>(
        h + C2_, CHID_, off5wb, 25*C2_, off5_b, offb, 50, 50, nullptr, nullptr);
    coeff_kernel<5><<<(B_*N_*25 + 255)/256, TB, 0, stream>>>(offb, 50, cidx, cwt);
    gemm_mfma<2,5><<<dim3(C2_/64, MT), TB, 0, stream>>>(
        h + C2_, CHID_, conv5wb, 25*C2_, conv5_b, dacc, C2_, C2_, cidx, cwt);
    gemm_mfma<1,5><<<dim3(C2_/64, MT), TB, 0, stream>>>(
        dacc, C2_, conv5wb, 25*C2_, conv5_b, h + C2_ /*ytok[:, 512:]*/, CHID_, C2_,
        nullptr, nullptr);

    // ---- LN + GELU, then fc2 -> fp32 out ----
    ln_gelu<<<B_*N_, TB, 0, stream>>>(h, ln_g, ln_b);
    gemm_mfma<0,1><<<dim3(CIN_/64, MT), TB, 0, stream>>>(
        h, CHID_, fc2wb, CHID_, fc2_b, out, CIN_, CIN_, nullptr, nullptr);
}